// Round 5
// baseline (331.789 us; speedup 1.0000x reference)
//
#include <hip/hip_runtime.h>

// DendralNeuron: out[b,d] = min( min_f(x[b,f]-Wmin[d,f]), min_f(Wmax[d,f]-x[b,f]) )
// R5: no-LDS design. R4 post-mortem: (a) z-split atomics caused 121 MB of HBM
// RMW traffic (the regression); (b) LDS DS-pipe is 1.5-6x oversubscribed vs
// VALU for all feasible tiles, while the loads are broadcast-heavy (xv: 4
// distinct 64B addrs/wave; nv/wv: 16 aligned 64B lines/wave) -> global loads
// coalesce to 64B-1KB per wave-instr and L1 (32KB/CU) holds the ~12KB/block
// working set. So: all operands straight from global (L1-served), zero
// barriers, zero DS. Split-K via workspace partials + tiny reduce kernel
// (no atomics). 8x2 thread tile, BM=128 BN=32, grid 8x16x7 = 896 blocks.

constexpr int F_DIM = 784;
constexpr int NQ = F_DIM / 4;      // 196 f-quads
constexpr int BM = 128;            // b rows per block (8/thread, stride 16)
constexpr int BN = 32;             // d cols per block (2/thread, stride 16)
constexpr int ZSPLIT = 7;          // 28 quads per slice (divisible by 4)

typedef float f4v __attribute__((ext_vector_type(4)));
typedef float f2v __attribute__((ext_vector_type(2)));

__global__ __launch_bounds__(256, 3)
void dendral_main(const float* __restrict__ x,
                  const float* __restrict__ wmin,
                  const float* __restrict__ wmax,
                  float* __restrict__ dst,   // ws slices, or out when zsplit==1
                  int D, long long sliceN, int zsplit) {
  const int t  = threadIdx.x;
  const int tx = t & 15;            // d: tx, tx+16
  const int ty = t >> 4;            // b: ty + 16*r, r<8
  const int b0 = blockIdx.x * BM;
  const int d0 = blockIdx.y * BN;
  const int z  = blockIdx.z;
  const int q0 = (z * NQ) / zsplit;
  const int q1 = ((z + 1) * NQ) / zsplit;   // q1-q0 always multiple of 4

  const float* xr[8];
#pragma unroll
  for (int r = 0; r < 8; ++r)
    xr[r] = x + (size_t)(b0 + ty + 16 * r) * F_DIM;
  const float* nr[2]; const float* wr[2];
#pragma unroll
  for (int c = 0; c < 2; ++c) {
    nr[c] = wmin + (size_t)(d0 + tx + 16 * c) * F_DIM;
    wr[c] = wmax + (size_t)(d0 + tx + 16 * c) * F_DIM;
  }

  float l1[8][2], mx[8][2];
#pragma unroll
  for (int r = 0; r < 8; ++r)
#pragma unroll
    for (int c = 0; c < 2; ++c) {
      l1[r][c] = __builtin_inff();
      mx[r][c] = -__builtin_inff();
    }

  for (int q = q0; q < q1; q += 4) {  // macro-iter: 4 quads, imm offsets 0..48B
#pragma unroll
    for (int k = 0; k < 4; ++k) {
      f4v xv[8], nv[2], wv[2];
#pragma unroll
      for (int r = 0; r < 8; ++r)     // 4 distinct addrs/wave -> 64B coalesced
        xv[r] = *(const f4v*)(xr[r] + (q + k) * 4);
#pragma unroll
      for (int c = 0; c < 2; ++c) {   // 16 aligned 64B lines/wave, L1-resident
        nv[c] = *(const f4v*)(nr[c] + (q + k) * 4);
        wv[c] = *(const f4v*)(wr[c] + (q + k) * 4);
      }
#pragma unroll
      for (int r = 0; r < 8; ++r)
#pragma unroll
        for (int c = 0; c < 2; ++c) {
          // L1 path: min_f(x - wmin); v2f32 subs -> v_pk_add_f32(neg)
          f2v a_lo = xv[r].xy - nv[c].xy;
          f2v a_hi = xv[r].zw - nv[c].zw;
          l1[r][c] = fminf(l1[r][c], fminf(a_lo.x, a_lo.y));  // v_min3
          l1[r][c] = fminf(l1[r][c], fminf(a_hi.x, a_hi.y));
          // L2 path: min_f(wmax - x) == -max_f(x - wmax)
          f2v u_lo = xv[r].xy - wv[c].xy;
          f2v u_hi = xv[r].zw - wv[c].zw;
          mx[r][c] = fmaxf(mx[r][c], fmaxf(u_lo.x, u_lo.y));  // v_max3
          mx[r][c] = fmaxf(mx[r][c], fmaxf(u_hi.x, u_hi.y));
        }
    }
  }

  float* o = dst + (size_t)z * sliceN;   // plain coalesced stores, no atomics
#pragma unroll
  for (int r = 0; r < 8; ++r)
#pragma unroll
    for (int c = 0; c < 2; ++c) {
      const int b = b0 + ty + 16 * r;
      const int d = d0 + tx + 16 * c;
      o[(size_t)b * D + d] = fminf(l1[r][c], -mx[r][c]);
    }
}

__global__ __launch_bounds__(256, 4)
void dendral_reduce(const float* __restrict__ ws, float* __restrict__ out,
                    long long sliceN, int zsplit) {
  const long long i = (long long)blockIdx.x * 256 + threadIdx.x;  // float4 idx
  f4v m = ((const f4v*)ws)[i];
  for (int z = 1; z < zsplit; ++z) {
    f4v v = ((const f4v*)(ws + (size_t)z * sliceN))[i];
    m.x = fminf(m.x, v.x); m.y = fminf(m.y, v.y);
    m.z = fminf(m.z, v.z); m.w = fminf(m.w, v.w);
  }
  ((f4v*)out)[i] = m;
}

extern "C" void kernel_launch(void* const* d_in, const int* in_sizes, int n_in,
                              void* d_out, int out_size, void* d_ws, size_t ws_size,
                              hipStream_t stream) {
  const float* x    = (const float*)d_in[0];
  const float* wmin = (const float*)d_in[1];
  const float* wmax = (const float*)d_in[2];
  float* out = (float*)d_out;
  const int B = in_sizes[0] / F_DIM;  // 1024
  const int D = in_sizes[1] / F_DIM;  // 512
  const long long sliceN = (long long)B * D;       // 524288

  // zsplit depends only on ws_size -> identical work every call (graph-safe).
  const int zsplit = (ws_size >= (size_t)ZSPLIT * sliceN * sizeof(float))
                         ? ZSPLIT : 1;
  float* dst = (zsplit > 1) ? (float*)d_ws : out;

  dim3 grid(B / BM, D / BN, zsplit);  // 8 x 16 x 7 = 896 blocks
  dendral_main<<<grid, 256, 0, stream>>>(x, wmin, wmax, dst, D, sliceN, zsplit);

  if (zsplit > 1) {
    dendral_reduce<<<(int)(sliceN / (256 * 4)), 256, 0, stream>>>(
        (const float*)d_ws, out, sliceN, zsplit);
  }
  (void)n_in; (void)out_size;
}

// Round 6
// 102.618 us; speedup vs baseline: 3.2332x; 3.2332x over previous
//
#include <hip/hip_runtime.h>

// DendralNeuron: out[b,d] = min( min_f(x[b,f]-Wmin[d,f]), min_f(Wmax[d,f]-x[b,f]) )
// R6: back to LDS (R5 no-LDS gather thrashed L1/L2: 262MB HBM fetch, 13% VALU).
// Fixes vs R3/R4:
//  - merged min: min(L1,L2) = min_f min(x-Wn, Wx-x) -> single acc array,
//    halves accumulator VGPRs -> affords TM=8 x TN=8 tile.
//  - 8x8 tile: LDS bytes/op = 4/TN + 8/TM = 1.5 B -> DS floor ~11.8us
//    (R3's 4x2 tile was 4 B/op -> ~31us DS-bound; that was the real limiter).
//  - single-wave blocks (64 thr): __syncthreads is convoy-free; no barrier
//    stalls (R1/R2 killer). BM=32 x BN=128, BK=8, grid 32x4x16 = 2048 blocks
//    = 8 waves/CU, independent progress.
//  - split-K via ws partials + reduce kernel (no atomics - R4's regression).

constexpr int F_DIM = 784;
constexpr int BK = 8;
constexpr int NCHUNK = F_DIM / BK;   // 98
constexpr int BM = 32;
constexpr int BN = 128;
constexpr int LSTR = BK + 4;         // 12 floats: 48B rows, 16B-aligned, 2-way banks max
constexpr int ZSPLIT = 16;

typedef float f4v __attribute__((ext_vector_type(4)));
typedef float f2v __attribute__((ext_vector_type(2)));

__global__ __launch_bounds__(64, 3)
void dendral_main(const float* __restrict__ x,
                  const float* __restrict__ wmin,
                  const float* __restrict__ wmax,
                  float* __restrict__ dst,    // ws slices, or out when zsplit==1
                  int D, long long sliceN, int zsplit) {
  __shared__ float lx[BM * LSTR];     // 1.5 KB
  __shared__ float lwn[BN * LSTR];    // 6 KB
  __shared__ float lwx[BN * LSTR];    // 6 KB

  const int l  = threadIdx.x;         // 0..63, one wave
  const int tx = l & 15;              // d cols: tx + 16*c, c<8
  const int ty = l >> 4;              // b rows: ty + 4*r, r<8
  const int b0 = blockIdx.x * BM;
  const int d0 = blockIdx.y * BN;
  const int z  = blockIdx.z;
  const int c0 = (z * NCHUNK) / zsplit;
  const int c1 = ((z + 1) * NCHUNK) / zsplit;

  // Staging map (per chunk of BK=8 floats):
  //  x tile 32x8 = 64 float4 -> 1/lane; W tiles 128x8 = 256 float4 -> 4/lane.
  const int sr = l >> 1;              // 0..31
  const int sc = (l & 1) << 2;        // 0 or 4
  const float* xg = x + (size_t)(b0 + sr) * F_DIM + sc;
  const float* ng = wmin + (size_t)(d0 + sr) * F_DIM + sc;
  const float* wg = wmax + (size_t)(d0 + sr) * F_DIM + sc;
  float* lds_x = lx + sr * LSTR + sc;
  float* lds_n = lwn + sr * LSTR + sc;
  float* lds_w = lwx + sr * LSTR + sc;
  const size_t wrow_step = (size_t)32 * F_DIM;   // +32 rows in global
  const int    lrow_step = 32 * LSTR;            // +32 rows in LDS

  float acc[8][8];
#pragma unroll
  for (int r = 0; r < 8; ++r)
#pragma unroll
    for (int c = 0; c < 8; ++c) acc[r][c] = __builtin_inff();

  for (int kc = c0; kc < c1; ++kc) {
    const int fo = kc * BK;
    // Global -> regs (async, vmcnt covers the burst).
    f4v gx = *(const f4v*)(xg + fo);
    f4v gn[4], gw[4];
#pragma unroll
    for (int i = 0; i < 4; ++i) {
      gn[i] = *(const f4v*)(ng + i * wrow_step + fo);
      gw[i] = *(const f4v*)(wg + i * wrow_step + fo);
    }
    __syncthreads();                  // WAR: prior reads done (1-wave: ~free)
    *(f4v*)lds_x = gx;
#pragma unroll
    for (int i = 0; i < 4; ++i) {
      *(f4v*)(lds_n + i * lrow_step) = gn[i];
      *(f4v*)(lds_w + i * lrow_step) = gw[i];
    }
    __syncthreads();                  // RAW: writes visible (1-wave: ~free)

#pragma unroll
    for (int f = 0; f < BK; f += 4) {
      f4v nv[8], wv[8];
#pragma unroll
      for (int c = 0; c < 8; ++c) {   // 16 distinct rows, 2-way banks (free)
        nv[c] = *(const f4v*)&lwn[(tx + 16 * c) * LSTR + f];
        wv[c] = *(const f4v*)&lwx[(tx + 16 * c) * LSTR + f];
      }
#pragma unroll
      for (int r = 0; r < 8; ++r) {
        f4v xv = *(const f4v*)&lx[(ty + 4 * r) * LSTR + f];  // 4 addrs: bcast
#pragma unroll
        for (int c = 0; c < 8; ++c) {
          f2v a_lo = xv.xy - nv[c].xy;   // v_pk_add_f32 (neg)
          f2v a_hi = xv.zw - nv[c].zw;
          f2v b_lo = wv[c].xy - xv.xy;
          f2v b_hi = wv[c].zw - xv.zw;
          float m = acc[r][c];
          m = fminf(m, fminf(a_lo.x, a_lo.y));   // v_min3
          m = fminf(m, fminf(a_hi.x, a_hi.y));
          m = fminf(m, fminf(b_lo.x, b_lo.y));
          m = fminf(m, fminf(b_hi.x, b_hi.y));
          acc[r][c] = m;
        }
      }
    }
  }

  float* o = dst + (size_t)z * sliceN;   // plain coalesced stores, no atomics
#pragma unroll
  for (int r = 0; r < 8; ++r)
#pragma unroll
    for (int c = 0; c < 8; ++c) {
      const int b = b0 + ty + 4 * r;
      const int d = d0 + tx + 16 * c;
      o[(size_t)b * D + d] = acc[r][c];
    }
}

__global__ __launch_bounds__(256, 4)
void dendral_reduce(const float* __restrict__ ws, float* __restrict__ out,
                    long long sliceN, int zsplit) {
  const long long i = (long long)blockIdx.x * 256 + threadIdx.x;  // float4 idx
  f4v m = ((const f4v*)ws)[i];
  for (int z = 1; z < zsplit; ++z) {
    f4v v = ((const f4v*)(ws + (size_t)z * sliceN))[i];
    m.x = fminf(m.x, v.x); m.y = fminf(m.y, v.y);
    m.z = fminf(m.z, v.z); m.w = fminf(m.w, v.w);
  }
  ((f4v*)out)[i] = m;
}

extern "C" void kernel_launch(void* const* d_in, const int* in_sizes, int n_in,
                              void* d_out, int out_size, void* d_ws, size_t ws_size,
                              hipStream_t stream) {
  const float* x    = (const float*)d_in[0];
  const float* wmin = (const float*)d_in[1];
  const float* wmax = (const float*)d_in[2];
  float* out = (float*)d_out;
  const int B = in_sizes[0] / F_DIM;  // 1024
  const int D = in_sizes[1] / F_DIM;  // 512
  const long long sliceN = (long long)B * D;       // 524288

  // zsplit depends only on ws_size -> identical work every call (graph-safe).
  const int zsplit = (ws_size >= (size_t)ZSPLIT * sliceN * sizeof(float))
                         ? ZSPLIT : 1;
  float* dst = (zsplit > 1) ? (float*)d_ws : out;

  dim3 grid(B / BM, D / BN, zsplit);  // 32 x 4 x 16 = 2048 wave-blocks
  dendral_main<<<grid, 64, 0, stream>>>(x, wmin, wmax, dst, D, sliceN, zsplit);

  if (zsplit > 1) {
    dendral_reduce<<<(int)(sliceN / (256 * 4)), 256, 0, stream>>>(
        (const float*)d_ws, out, sliceN, zsplit);
  }
  (void)n_in; (void)out_size;
}